// Round 7
// baseline (350.873 us; speedup 1.0000x reference)
//
#include <hip/hip_runtime.h>
#include <hip/hip_bf16.h>
#include <float.h>

#define B_ 64
#define H_ 1024
#define S_ 1024
#define V_ 50257
#define L_ 3
#define G3H 3072      // 3*H
#define N_GATES 6144  // 2*3H fused gi|gh
#define NT_K 16       // 1024 / 64 k-tiles in output GEMM

typedef __attribute__((ext_vector_type(8))) short short8v;  // 8 bf16 (4 VGPRs)
typedef __attribute__((ext_vector_type(4))) float f32x4;    // MFMA accumulator

// round-to-nearest f32 -> bf16 bits
__device__ __forceinline__ ushort rnd_bf16(float x) {
    uint u = __float_as_uint(x);
    return (ushort)((u + 0x7fffu + ((u >> 16) & 1u)) >> 16);
}

// exact split x = hi + lo (hi = truncated bf16, lo = rounded residual)
__device__ __forceinline__ void split_bf16(float x, ushort& hi, ushort& lo) {
    uint u = __float_as_uint(x);
    uint h = u & 0xffff0000u;
    hi = (ushort)(h >> 16);
    float r = x - __uint_as_float(h);
    uint ur = __float_as_uint(r);
    lo = (ushort)((ur + 0x7fffu + ((ur >> 16) & 1u)) >> 16);
}

// LDS XOR swizzle for fp32 GEMMs: permute 16B chunks within a row.
__device__ __forceinline__ int swzi(int kk, int m) {
    return (((m >> 2) ^ ((kk >> 2) & 7)) << 2) | (m & 3);
}

// ---------------------------------------------------------------------------
// Embedding gather: x0[b][h] = emb[seq[b]][h]
__global__ __launch_bounds__(256) void embed_k(const int* __restrict__ seq,
                                               const float* __restrict__ emb,
                                               float* __restrict__ x0) {
    int idx = blockIdx.x * 256 + threadIdx.x;  // 65536 total
    int b = idx >> 10, h = idx & 1023;
    x0[idx] = emb[(size_t)seq[b] * H_ + h];
}

// ---------------------------------------------------------------------------
// Generic M=64 fp32 GEMM (GRU gates + concat): C[m][n] = sum_k A[m][k]*W[n][k]
// Tile 64x64, KT=32, swizzled LDS, K-split partials to Cpart[kc][m][n].
__global__ __launch_bounds__(256) void gemm_m64(
    const float* __restrict__ A0, const float* __restrict__ A1, int lda,
    const float* __restrict__ W0, const float* __restrict__ W1, int ldw,
    int Nhalf, float* __restrict__ Cpart, int N, int K) {
    __shared__ float As[32 * 68];
    __shared__ float Ws[32 * 68];

    int n0 = blockIdx.x * 64;
    const float* A = A0;
    const float* W = W0;
    int ncol0 = n0;
    if (n0 >= Nhalf) { A = A1; W = W1; ncol0 = n0 - Nhalf; }

    int tid = threadIdx.x;
    int tx = tid & 15, ty = tid >> 4;
    int row = tid >> 3;  // 0..31
    int cg = tid & 7;    // k group of 4

    float acc[4][4] = {};

    int kChunk = K / gridDim.y;
    int k0b = blockIdx.y * kChunk;

    for (int k0 = k0b; k0 < k0b + kChunk; k0 += 32) {
        float4 a0 = *(const float4*)&A[(size_t)row * lda + k0 + cg * 4];
        float4 a1 = *(const float4*)&A[(size_t)(row + 32) * lda + k0 + cg * 4];
        float4 w0 = *(const float4*)&W[(size_t)(ncol0 + row) * ldw + k0 + cg * 4];
        float4 w1 = *(const float4*)&W[(size_t)(ncol0 + row + 32) * ldw + k0 + cg * 4];
        const float* fa0 = (const float*)&a0;
        const float* fa1 = (const float*)&a1;
        const float* fw0 = (const float*)&w0;
        const float* fw1 = (const float*)&w1;
#pragma unroll
        for (int j = 0; j < 4; j++) {
            int kk = cg * 4 + j;
            As[kk * 68 + swzi(kk, row)] = fa0[j];
            As[kk * 68 + swzi(kk, row + 32)] = fa1[j];
            Ws[kk * 68 + swzi(kk, row)] = fw0[j];
            Ws[kk * 68 + swzi(kk, row + 32)] = fw1[j];
        }
        __syncthreads();
#pragma unroll
        for (int kk = 0; kk < 32; kk++) {
            int cgk = (kk >> 2) & 7;
            float4 av = *(const float4*)&As[kk * 68 + ((ty ^ cgk) << 2)];
            float4 wv = *(const float4*)&Ws[kk * 68 + ((tx ^ cgk) << 2)];
            acc[0][0] += av.x * wv.x; acc[0][1] += av.x * wv.y;
            acc[0][2] += av.x * wv.z; acc[0][3] += av.x * wv.w;
            acc[1][0] += av.y * wv.x; acc[1][1] += av.y * wv.y;
            acc[1][2] += av.y * wv.z; acc[1][3] += av.y * wv.w;
            acc[2][0] += av.z * wv.x; acc[2][1] += av.z * wv.y;
            acc[2][2] += av.z * wv.z; acc[2][3] += av.z * wv.w;
            acc[3][0] += av.w * wv.x; acc[3][1] += av.w * wv.y;
            acc[3][2] += av.w * wv.z; acc[3][3] += av.w * wv.w;
        }
        __syncthreads();
    }

    float* P = Cpart + (size_t)blockIdx.y * 64 * N;
#pragma unroll
    for (int i = 0; i < 4; i++) {
        int m = ty * 4 + i;
#pragma unroll
        for (int j = 0; j < 4; j++) {
            int n = n0 + tx * 4 + j;
            P[(size_t)m * N + n] = acc[i][j];
        }
    }
}

// ---------------------------------------------------------------------------
// GRU gate combine: 4 K-split partials of fused [gi | gh] + biases -> h_out
__global__ __launch_bounds__(256) void gru_combine_k(
    const float* __restrict__ P, const float* __restrict__ b_ih,
    const float* __restrict__ b_hh, const float* __restrict__ hprev,
    float* __restrict__ hout) {
    int idx = blockIdx.x * 256 + threadIdx.x;  // 65536
    int b = idx >> 10, j = idx & 1023;
    const size_t stride = (size_t)64 * N_GATES;
    const float* rowp = P + (size_t)b * N_GATES;

    float ir = 0.f, iz = 0.f, in_ = 0.f, hr = 0.f, hz = 0.f, hn = 0.f;
#pragma unroll
    for (int kc = 0; kc < 4; kc++) {
        const float* p = rowp + kc * stride;
        ir += p[j];        iz += p[j + 1024];        in_ += p[j + 2048];
        hr += p[3072 + j]; hz += p[3072 + j + 1024]; hn += p[3072 + j + 2048];
    }
    ir += b_ih[j]; iz += b_ih[j + 1024]; in_ += b_ih[j + 2048];
    hr += b_hh[j]; hz += b_hh[j + 1024]; hn += b_hh[j + 2048];

    float r = 1.f / (1.f + __expf(-(ir + hr)));
    float z = 1.f / (1.f + __expf(-(iz + hz)));
    float n = tanhf(in_ + r * hn);
    float hp = hprev[idx];
    hout[idx] = (1.f - z) * n + z * hp;
}

// ---------------------------------------------------------------------------
// Fused attention pass 1: one enc read -> raw scores + online-softmax context
// partials. grid = 64 b * 16 sc; 4 waves/block, each wave owns 16 s rows.
__global__ __launch_bounds__(256) void attn_pass1(
    const float* __restrict__ rnn, const float* __restrict__ enc,
    float* __restrict__ scores, float* __restrict__ ctxPart,
    float* __restrict__ chunkMax) {
    __shared__ float lm[4];
    __shared__ float lc[4][1024];

    int bid = blockIdx.x;
    int b = bid >> 4, scv = bid & 15;
    int tid = threadIdx.x;
    int w = tid >> 6, lane = tid & 63;

    const float4* rr = (const float4*)(rnn + (size_t)b * H_);
    float4 r0 = rr[0 * 64 + lane], r1 = rr[1 * 64 + lane];
    float4 r2 = rr[2 * 64 + lane], r3 = rr[3 * 64 + lane];

    float m = -FLT_MAX;
    float4 c0 = {0, 0, 0, 0}, c1 = {0, 0, 0, 0}, c2 = {0, 0, 0, 0}, c3 = {0, 0, 0, 0};

    int s0 = scv * 64 + w * 16;
    for (int si = 0; si < 16; si++) {
        int s = s0 + si;
        const float4* er = (const float4*)(enc + ((size_t)s * B_ + b) * H_);
        float4 e0 = er[0 * 64 + lane], e1 = er[1 * 64 + lane];
        float4 e2 = er[2 * 64 + lane], e3 = er[3 * 64 + lane];

        float d = e0.x * r0.x + e0.y * r0.y + e0.z * r0.z + e0.w * r0.w;
        d += e1.x * r1.x + e1.y * r1.y + e1.z * r1.z + e1.w * r1.w;
        d += e2.x * r2.x + e2.y * r2.y + e2.z * r2.z + e2.w * r2.w;
        d += e3.x * r3.x + e3.y * r3.y + e3.z * r3.z + e3.w * r3.w;
#pragma unroll
        for (int off = 32; off; off >>= 1) d += __shfl_xor(d, off, 64);
        if (lane == 0) scores[(size_t)b * S_ + s] = d;

        if (d > m) {  // wave-uniform (d identical on all lanes)
            float scale = __expf(m - d);
            c0.x *= scale; c0.y *= scale; c0.z *= scale; c0.w *= scale;
            c1.x *= scale; c1.y *= scale; c1.z *= scale; c1.w *= scale;
            c2.x *= scale; c2.y *= scale; c2.z *= scale; c2.w *= scale;
            c3.x *= scale; c3.y *= scale; c3.z *= scale; c3.w *= scale;
            m = d;
        }
        float p = __expf(d - m);
        c0.x += p * e0.x; c0.y += p * e0.y; c0.z += p * e0.z; c0.w += p * e0.w;
        c1.x += p * e1.x; c1.y += p * e1.y; c1.z += p * e1.z; c1.w += p * e1.w;
        c2.x += p * e2.x; c2.y += p * e2.y; c2.z += p * e2.z; c2.w += p * e2.w;
        c3.x += p * e3.x; c3.y += p * e3.y; c3.z += p * e3.z; c3.w += p * e3.w;
    }

    if (lane == 0) lm[w] = m;
    __syncthreads();
    float M = fmaxf(fmaxf(lm[0], lm[1]), fmaxf(lm[2], lm[3]));
    float sw = __expf(m - M);
    float4* lw = (float4*)&lc[w][0];
    float4 t;
    t.x = c0.x * sw; t.y = c0.y * sw; t.z = c0.z * sw; t.w = c0.w * sw; lw[0 * 64 + lane] = t;
    t.x = c1.x * sw; t.y = c1.y * sw; t.z = c1.z * sw; t.w = c1.w * sw; lw[1 * 64 + lane] = t;
    t.x = c2.x * sw; t.y = c2.y * sw; t.z = c2.z * sw; t.w = c2.w * sw; lw[2 * 64 + lane] = t;
    t.x = c3.x * sw; t.y = c3.y * sw; t.z = c3.z * sw; t.w = c3.w * sw; lw[3 * 64 + lane] = t;
    __syncthreads();

    float4 s4 = *(const float4*)&lc[0][tid * 4];
    float4 a1 = *(const float4*)&lc[1][tid * 4];
    float4 a2 = *(const float4*)&lc[2][tid * 4];
    float4 a3 = *(const float4*)&lc[3][tid * 4];
    s4.x += a1.x + a2.x + a3.x; s4.y += a1.y + a2.y + a3.y;
    s4.z += a1.z + a2.z + a3.z; s4.w += a1.w + a2.w + a3.w;
    *(float4*)&ctxPart[(size_t)bid * H_ + tid * 4] = s4;
    if (tid == 0) chunkMax[bid] = M;
}

// ---------------------------------------------------------------------------
// Attention pass 2 (per b): global softmax -> attn output, rescale+sum chunk
// contexts, assemble concat_in = [rnn | ctx].
__global__ __launch_bounds__(256) void attn_pass2(
    const float* __restrict__ scores, const float* __restrict__ chunkMax,
    const float* __restrict__ ctxPart, const float* __restrict__ rnn,
    float* __restrict__ attn, float* __restrict__ concat_in) {
    __shared__ float red[256];
    int b = blockIdx.x, tid = threadIdx.x;

    float v[4];
#pragma unroll
    for (int q = 0; q < 4; q++) v[q] = scores[(size_t)b * S_ + q * 256 + tid];
    float mx = fmaxf(fmaxf(v[0], v[1]), fmaxf(v[2], v[3]));
    red[tid] = mx; __syncthreads();
    for (int s = 128; s; s >>= 1) {
        if (tid < s) red[tid] = fmaxf(red[tid], red[tid + s]);
        __syncthreads();
    }
    float M = red[0]; __syncthreads();
    float e[4], sum = 0.f;
#pragma unroll
    for (int q = 0; q < 4; q++) { e[q] = __expf(v[q] - M); sum += e[q]; }
    red[tid] = sum; __syncthreads();
    for (int s = 128; s; s >>= 1) {
        if (tid < s) red[tid] += red[tid + s];
        __syncthreads();
    }
    float inv = 1.f / red[0];
#pragma unroll
    for (int q = 0; q < 4; q++) attn[(size_t)b * S_ + q * 256 + tid] = e[q] * inv;

    float4 acc = {0, 0, 0, 0};
#pragma unroll
    for (int c = 0; c < 16; c++) {
        float scl = __expf(chunkMax[b * 16 + c] - M);
        float4 part = *(const float4*)&ctxPart[((size_t)b * 16 + c) * H_ + tid * 4];
        acc.x += scl * part.x; acc.y += scl * part.y;
        acc.z += scl * part.z; acc.w += scl * part.w;
    }
    acc.x *= inv; acc.y *= inv; acc.z *= inv; acc.w *= inv;
    *(float4*)&concat_in[(size_t)b * 2048 + 1024 + tid * 4] = acc;
    *(float4*)&concat_in[(size_t)b * 2048 + tid * 4] =
        *(const float4*)&rnn[(size_t)b * H_ + tid * 4];
}

// ---------------------------------------------------------------------------
// Concat combine: sum 8 K-split partials + bias, tanh; emit exact bf16
// hi/lo split of the result for the MFMA output GEMM.
__global__ __launch_bounds__(256) void concat_combine_k(const float* __restrict__ P,
                                                        const float* __restrict__ bias,
                                                        ushort* __restrict__ Ahi,
                                                        ushort* __restrict__ Alo) {
    int idx = blockIdx.x * 256 + threadIdx.x;  // 65536
    int b = idx >> 10, h = idx & 1023;
    float s = 0.f;
#pragma unroll
    for (int kc = 0; kc < 8; kc++) s += P[(size_t)kc * 65536 + (size_t)b * H_ + h];
    float v = tanhf(s + bias[h]);
    ushort hi, lo;
    split_bf16(v, hi, lo);
    Ahi[idx] = hi;
    Alo[idx] = lo;
}

// ---------------------------------------------------------------------------
// Output GEMM: out[64][V] = (Ahi+Alo)[64][1024] x bf16(W[V][1024])^T + bias.
// LDS-staged W (fixes the 4KB-row-stride channel aliasing: staging reads are
// 256B-contiguous per 16 lanes), double-buffered 64x64 fp32 tiles, 4 waves;
// wave w owns 16 output cols. MFMA 16x16x32 bf16, A hi/lo exact split.
__global__ __launch_bounds__(256) void gemm_out_bf16(
    const ushort* __restrict__ Ahi, const ushort* __restrict__ Alo,
    const float* __restrict__ W, const float* __restrict__ bias,
    float* __restrict__ out) {
    __shared__ float Ws[2][64 * 68];

    int tid = threadIdx.x;
    int w = tid >> 6, l = tid & 63;
    int lr = l & 15;  // col within wave's 16-col tile / A row within 16
    int lk = l >> 4;  // k-subgroup 0..3

    int n0 = blockIdx.x * 64;
    int col = n0 + w * 16 + lr;  // this lane's output col
    bool cv = col < V_;

    // staging map: thread loads W[n0 + it*16 + (tid>>4)][(tid&15)*4 .. +4]
    // -> per wave instruction: 4 rows x 256B contiguous each.
    int srow = tid >> 4;       // 0..15
    int skk = (tid & 15) * 4;  // 0..60

    f32x4 acc[4];
#pragma unroll
    for (int mt = 0; mt < 4; mt++) acc[mt] = (f32x4){0.f, 0.f, 0.f, 0.f};

    float4 sreg[4];
    auto load_regs = [&](int kt) {
        int k0 = kt * 64;
#pragma unroll
        for (int it = 0; it < 4; it++) {
            int r = n0 + it * 16 + srow;
            const float* src = W + (size_t)(r < V_ ? r : 0) * H_ + k0 + skk;
            sreg[it] = *(const float4*)src;
        }
    };
    auto write_lds = [&](int buf) {
        float* dst = &Ws[buf][0];
#pragma unroll
        for (int it = 0; it < 4; it++)
            *(float4*)&dst[(it * 16 + srow) * 68 + skk] = sreg[it];
    };

    union SV { short8v v; ushort u[8]; };

    load_regs(0);
    write_lds(0);
    __syncthreads();

    for (int kt = 0; kt < NT_K; kt++) {
        if (kt + 1 < NT_K) load_regs(kt + 1);  // HBM loads fly under compute

        const float* buf = &Ws[kt & 1][0];
#pragma unroll
        for (int ks = 0; ks < 2; ks++) {
            int kin = ks * 32 + lk * 8;   // k within tile for this lane
            int kbg = kt * 64 + kin;      // global k

            // A fragments (bf16 hi/lo, L2-resident)
            short8v ah[4], al[4];
#pragma unroll
            for (int mt = 0; mt < 4; mt++) {
                int mr = mt * 16 + lr;
                ah[mt] = *(const short8v*)&Ahi[(size_t)mr * H_ + kbg];
                al[mt] = *(const short8v*)&Alo[(size_t)mr * H_ + kbg];
            }

            // W fragment from LDS (8 fp32 -> bf16)
            const float* wp = &buf[(w * 16 + lr) * 68 + kin];
            float4 wv0 = *(const float4*)wp;
            float4 wv1 = *(const float4*)(wp + 4);
            SV wf;
            const float* f0 = (const float*)&wv0;
            const float* f1 = (const float*)&wv1;
#pragma unroll
            for (int j = 0; j < 4; j++) {
                wf.u[j] = rnd_bf16(f0[j]);
                wf.u[j + 4] = rnd_bf16(f1[j]);
            }

#pragma unroll
            for (int mt = 0; mt < 4; mt++) {
                acc[mt] = __builtin_amdgcn_mfma_f32_16x16x32_bf16(ah[mt], wf.v, acc[mt], 0, 0, 0);
                acc[mt] = __builtin_amdgcn_mfma_f32_16x16x32_bf16(al[mt], wf.v, acc[mt], 0, 0, 0);
            }
        }

        if (kt + 1 < NT_K) {
            __syncthreads();               // everyone done reading buf[kt&1]? (reads of NEXT buf finished last iter)
            write_lds((kt + 1) & 1);       // stage next tile
            __syncthreads();               // staged data visible
        }
    }

    // Epilogue: D col = lane&15 tile col; row = (l>>4)*4 + r + mt*16
    float bb = cv ? bias[col] : 0.f;
#pragma unroll
    for (int mt = 0; mt < 4; mt++) {
#pragma unroll
        for (int r = 0; r < 4; r++) {
            int row = mt * 16 + lk * 4 + r;
            if (cv) out[(size_t)row * V_ + col] = acc[mt][r] + bb;
        }
    }
}

// ---------------------------------------------------------------------------
extern "C" void kernel_launch(void* const* d_in, const int* in_sizes, int n_in,
                              void* d_out, int out_size, void* d_ws, size_t ws_size,
                              hipStream_t stream) {
    const int* seq = (const int*)d_in[0];
    const float* last_hidden = (const float*)d_in[1];
    const float* enc = (const float*)d_in[2];
    const float* emb = (const float*)d_in[3];
    const float* w_ih = (const float*)d_in[4];
    const float* w_hh = (const float*)d_in[5];
    const float* b_ih = (const float*)d_in[6];
    const float* b_hh = (const float*)d_in[7];
    const float* concat_w = (const float*)d_in[8];
    const float* concat_b = (const float*)d_in[9];
    const float* out_w = (const float*)d_in[10];
    const float* out_b = (const float*)d_in[11];

    float* out = (float*)d_out;                           // (B,V)
    float* out_hidden = out + (size_t)B_ * V_;            // (L,B,H)
    float* out_attn = out_hidden + (size_t)L_ * B_ * H_;  // (B,1,S)

    float* ws = (float*)d_ws;
    float* x0 = ws;                        // 65536
    float* gatesP = x0 + 65536;            // 4*64*6144 = 1572864
    float* scores = gatesP + 1572864;      // 65536
    float* chunkMax = scores + 65536;      // 1024
    float* ctxPart = chunkMax + 1024;      // 1048576
    float* concat_in = ctxPart + 1048576;  // 131072
    float* concatP = concat_in + 131072;   // 524288
    ushort* Ahi = (ushort*)(concatP + 524288);  // 65536 ushort
    ushort* Alo = Ahi + 65536;                  // 65536 ushort

    // 1. Embedding
    embed_k<<<256, 256, 0, stream>>>(seq, emb, x0);

    // 2. GRU layers
    for (int l = 0; l < L_; l++) {
        const float* xl = (l == 0) ? x0 : out_hidden + (size_t)(l - 1) * B_ * H_;
        const float* hl = last_hidden + (size_t)l * B_ * H_;
        gemm_m64<<<dim3(N_GATES / 64, 4), 256, 0, stream>>>(
            xl, hl, H_,
            w_ih + (size_t)l * G3H * H_, w_hh + (size_t)l * G3H * H_, H_, G3H,
            gatesP, N_GATES, H_);
        gru_combine_k<<<256, 256, 0, stream>>>(gatesP, b_ih + (size_t)l * G3H,
                                               b_hh + (size_t)l * G3H, hl,
                                               out_hidden + (size_t)l * B_ * H_);
    }
    const float* rnn = out_hidden + (size_t)2 * B_ * H_;

    // 3. Fused attention (single enc pass) + combine/assemble
    attn_pass1<<<1024, 256, 0, stream>>>(rnn, enc, scores, ctxPart, chunkMax);
    attn_pass2<<<64, 256, 0, stream>>>(scores, chunkMax, ctxPart, rnn,
                                       out_attn, concat_in);

    // 4. Concat GEMM (K=2048, 8-way K-split) + tanh combine (+ bf16 split)
    gemm_m64<<<dim3(16, 8), 256, 0, stream>>>(
        concat_in, concat_in, 2048, concat_w, concat_w, 2048, 1 << 30,
        concatP, H_, 2048);
    concat_combine_k<<<256, 256, 0, stream>>>(concatP, concat_b, Ahi, Alo);

    // 5. Output GEMM: LDS-staged W, bf16 MFMA, direct store with bias
    gemm_out_bf16<<<(V_ + 63) / 64, 256, 0, stream>>>(Ahi, Alo, out_w, out_b, out);
}

// Round 8
// 218.760 us; speedup vs baseline: 1.6039x; 1.6039x over previous
//
#include <hip/hip_runtime.h>
#include <hip/hip_bf16.h>
#include <float.h>

#define B_ 64
#define H_ 1024
#define S_ 1024
#define V_ 50257
#define L_ 3
#define G3H 3072      // 3*H
#define N_GATES 6144  // 2*3H fused gi|gh
#define NT_K 16       // 1024 / 64 k-tiles in output GEMM

typedef __attribute__((ext_vector_type(8))) short short8v;  // 8 bf16 (4 VGPRs)
typedef __attribute__((ext_vector_type(4))) float f32x4;    // MFMA accumulator

// round-to-nearest f32 -> bf16 bits
__device__ __forceinline__ ushort rnd_bf16(float x) {
    uint u = __float_as_uint(x);
    return (ushort)((u + 0x7fffu + ((u >> 16) & 1u)) >> 16);
}

// exact split x = hi + lo (hi = truncated bf16, lo = rounded residual)
__device__ __forceinline__ void split_bf16(float x, ushort& hi, ushort& lo) {
    uint u = __float_as_uint(x);
    uint h = u & 0xffff0000u;
    hi = (ushort)(h >> 16);
    float r = x - __uint_as_float(h);
    uint ur = __float_as_uint(r);
    lo = (ushort)((ur + 0x7fffu + ((ur >> 16) & 1u)) >> 16);
}

// LDS XOR swizzle for fp32 GEMMs: permute 16B chunks within a row.
__device__ __forceinline__ int swzi(int kk, int m) {
    return (((m >> 2) ^ ((kk >> 2) & 7)) << 2) | (m & 3);
}

// ---------------------------------------------------------------------------
// Embedding gather: x0[b][h] = emb[seq[b]][h]
__global__ __launch_bounds__(256) void embed_k(const int* __restrict__ seq,
                                               const float* __restrict__ emb,
                                               float* __restrict__ x0) {
    int idx = blockIdx.x * 256 + threadIdx.x;  // 65536 total
    int b = idx >> 10, h = idx & 1023;
    x0[idx] = emb[(size_t)seq[b] * H_ + h];
}

// ---------------------------------------------------------------------------
// Generic M=64 fp32 GEMM (GRU gates + concat): C[m][n] = sum_k A[m][k]*W[n][k]
// Tile 64x64, KT=32, swizzled LDS, K-split partials to Cpart[kc][m][n].
__global__ __launch_bounds__(256) void gemm_m64(
    const float* __restrict__ A0, const float* __restrict__ A1, int lda,
    const float* __restrict__ W0, const float* __restrict__ W1, int ldw,
    int Nhalf, float* __restrict__ Cpart, int N, int K) {
    __shared__ float As[32 * 68];
    __shared__ float Ws[32 * 68];

    int n0 = blockIdx.x * 64;
    const float* A = A0;
    const float* W = W0;
    int ncol0 = n0;
    if (n0 >= Nhalf) { A = A1; W = W1; ncol0 = n0 - Nhalf; }

    int tid = threadIdx.x;
    int tx = tid & 15, ty = tid >> 4;
    int row = tid >> 3;  // 0..31
    int cg = tid & 7;    // k group of 4

    float acc[4][4] = {};

    int kChunk = K / gridDim.y;
    int k0b = blockIdx.y * kChunk;

    for (int k0 = k0b; k0 < k0b + kChunk; k0 += 32) {
        float4 a0 = *(const float4*)&A[(size_t)row * lda + k0 + cg * 4];
        float4 a1 = *(const float4*)&A[(size_t)(row + 32) * lda + k0 + cg * 4];
        float4 w0 = *(const float4*)&W[(size_t)(ncol0 + row) * ldw + k0 + cg * 4];
        float4 w1 = *(const float4*)&W[(size_t)(ncol0 + row + 32) * ldw + k0 + cg * 4];
        const float* fa0 = (const float*)&a0;
        const float* fa1 = (const float*)&a1;
        const float* fw0 = (const float*)&w0;
        const float* fw1 = (const float*)&w1;
#pragma unroll
        for (int j = 0; j < 4; j++) {
            int kk = cg * 4 + j;
            As[kk * 68 + swzi(kk, row)] = fa0[j];
            As[kk * 68 + swzi(kk, row + 32)] = fa1[j];
            Ws[kk * 68 + swzi(kk, row)] = fw0[j];
            Ws[kk * 68 + swzi(kk, row + 32)] = fw1[j];
        }
        __syncthreads();
#pragma unroll
        for (int kk = 0; kk < 32; kk++) {
            int cgk = (kk >> 2) & 7;
            float4 av = *(const float4*)&As[kk * 68 + ((ty ^ cgk) << 2)];
            float4 wv = *(const float4*)&Ws[kk * 68 + ((tx ^ cgk) << 2)];
            acc[0][0] += av.x * wv.x; acc[0][1] += av.x * wv.y;
            acc[0][2] += av.x * wv.z; acc[0][3] += av.x * wv.w;
            acc[1][0] += av.y * wv.x; acc[1][1] += av.y * wv.y;
            acc[1][2] += av.y * wv.z; acc[1][3] += av.y * wv.w;
            acc[2][0] += av.z * wv.x; acc[2][1] += av.z * wv.y;
            acc[2][2] += av.z * wv.z; acc[2][3] += av.z * wv.w;
            acc[3][0] += av.w * wv.x; acc[3][1] += av.w * wv.y;
            acc[3][2] += av.w * wv.z; acc[3][3] += av.w * wv.w;
        }
        __syncthreads();
    }

    float* P = Cpart + (size_t)blockIdx.y * 64 * N;
#pragma unroll
    for (int i = 0; i < 4; i++) {
        int m = ty * 4 + i;
#pragma unroll
        for (int j = 0; j < 4; j++) {
            int n = n0 + tx * 4 + j;
            P[(size_t)m * N + n] = acc[i][j];
        }
    }
}

// ---------------------------------------------------------------------------
// GRU gate combine: 4 K-split partials of fused [gi | gh] + biases -> h_out
__global__ __launch_bounds__(256) void gru_combine_k(
    const float* __restrict__ P, const float* __restrict__ b_ih,
    const float* __restrict__ b_hh, const float* __restrict__ hprev,
    float* __restrict__ hout) {
    int idx = blockIdx.x * 256 + threadIdx.x;  // 65536
    int b = idx >> 10, j = idx & 1023;
    const size_t stride = (size_t)64 * N_GATES;
    const float* rowp = P + (size_t)b * N_GATES;

    float ir = 0.f, iz = 0.f, in_ = 0.f, hr = 0.f, hz = 0.f, hn = 0.f;
#pragma unroll
    for (int kc = 0; kc < 4; kc++) {
        const float* p = rowp + kc * stride;
        ir += p[j];        iz += p[j + 1024];        in_ += p[j + 2048];
        hr += p[3072 + j]; hz += p[3072 + j + 1024]; hn += p[3072 + j + 2048];
    }
    ir += b_ih[j]; iz += b_ih[j + 1024]; in_ += b_ih[j + 2048];
    hr += b_hh[j]; hz += b_hh[j + 1024]; hn += b_hh[j + 2048];

    float r = 1.f / (1.f + __expf(-(ir + hr)));
    float z = 1.f / (1.f + __expf(-(iz + hz)));
    float n = tanhf(in_ + r * hn);
    float hp = hprev[idx];
    hout[idx] = (1.f - z) * n + z * hp;
}

// ---------------------------------------------------------------------------
// Fused attention pass 1: one enc read -> raw scores + online-softmax context
// partials. grid = 64 b * 16 sc; 4 waves/block, each wave owns 16 s rows.
__global__ __launch_bounds__(256) void attn_pass1(
    const float* __restrict__ rnn, const float* __restrict__ enc,
    float* __restrict__ scores, float* __restrict__ ctxPart,
    float* __restrict__ chunkMax) {
    __shared__ float lm[4];
    __shared__ float lc[4][1024];

    int bid = blockIdx.x;
    int b = bid >> 4, scv = bid & 15;
    int tid = threadIdx.x;
    int w = tid >> 6, lane = tid & 63;

    const float4* rr = (const float4*)(rnn + (size_t)b * H_);
    float4 r0 = rr[0 * 64 + lane], r1 = rr[1 * 64 + lane];
    float4 r2 = rr[2 * 64 + lane], r3 = rr[3 * 64 + lane];

    float m = -FLT_MAX;
    float4 c0 = {0, 0, 0, 0}, c1 = {0, 0, 0, 0}, c2 = {0, 0, 0, 0}, c3 = {0, 0, 0, 0};

    int s0 = scv * 64 + w * 16;
    for (int si = 0; si < 16; si++) {
        int s = s0 + si;
        const float4* er = (const float4*)(enc + ((size_t)s * B_ + b) * H_);
        float4 e0 = er[0 * 64 + lane], e1 = er[1 * 64 + lane];
        float4 e2 = er[2 * 64 + lane], e3 = er[3 * 64 + lane];

        float d = e0.x * r0.x + e0.y * r0.y + e0.z * r0.z + e0.w * r0.w;
        d += e1.x * r1.x + e1.y * r1.y + e1.z * r1.z + e1.w * r1.w;
        d += e2.x * r2.x + e2.y * r2.y + e2.z * r2.z + e2.w * r2.w;
        d += e3.x * r3.x + e3.y * r3.y + e3.z * r3.z + e3.w * r3.w;
#pragma unroll
        for (int off = 32; off; off >>= 1) d += __shfl_xor(d, off, 64);
        if (lane == 0) scores[(size_t)b * S_ + s] = d;

        if (d > m) {  // wave-uniform (d identical on all lanes)
            float scale = __expf(m - d);
            c0.x *= scale; c0.y *= scale; c0.z *= scale; c0.w *= scale;
            c1.x *= scale; c1.y *= scale; c1.z *= scale; c1.w *= scale;
            c2.x *= scale; c2.y *= scale; c2.z *= scale; c2.w *= scale;
            c3.x *= scale; c3.y *= scale; c3.z *= scale; c3.w *= scale;
            m = d;
        }
        float p = __expf(d - m);
        c0.x += p * e0.x; c0.y += p * e0.y; c0.z += p * e0.z; c0.w += p * e0.w;
        c1.x += p * e1.x; c1.y += p * e1.y; c1.z += p * e1.z; c1.w += p * e1.w;
        c2.x += p * e2.x; c2.y += p * e2.y; c2.z += p * e2.z; c2.w += p * e2.w;
        c3.x += p * e3.x; c3.y += p * e3.y; c3.z += p * e3.z; c3.w += p * e3.w;
    }

    if (lane == 0) lm[w] = m;
    __syncthreads();
    float M = fmaxf(fmaxf(lm[0], lm[1]), fmaxf(lm[2], lm[3]));
    float sw = __expf(m - M);
    float4* lw = (float4*)&lc[w][0];
    float4 t;
    t.x = c0.x * sw; t.y = c0.y * sw; t.z = c0.z * sw; t.w = c0.w * sw; lw[0 * 64 + lane] = t;
    t.x = c1.x * sw; t.y = c1.y * sw; t.z = c1.z * sw; t.w = c1.w * sw; lw[1 * 64 + lane] = t;
    t.x = c2.x * sw; t.y = c2.y * sw; t.z = c2.z * sw; t.w = c2.w * sw; lw[2 * 64 + lane] = t;
    t.x = c3.x * sw; t.y = c3.y * sw; t.z = c3.z * sw; t.w = c3.w * sw; lw[3 * 64 + lane] = t;
    __syncthreads();

    float4 s4 = *(const float4*)&lc[0][tid * 4];
    float4 a1 = *(const float4*)&lc[1][tid * 4];
    float4 a2 = *(const float4*)&lc[2][tid * 4];
    float4 a3 = *(const float4*)&lc[3][tid * 4];
    s4.x += a1.x + a2.x + a3.x; s4.y += a1.y + a2.y + a3.y;
    s4.z += a1.z + a2.z + a3.z; s4.w += a1.w + a2.w + a3.w;
    *(float4*)&ctxPart[(size_t)bid * H_ + tid * 4] = s4;
    if (tid == 0) chunkMax[bid] = M;
}

// ---------------------------------------------------------------------------
// Attention pass 2 (per b): global softmax -> attn output, rescale+sum chunk
// contexts, assemble concat_in = [rnn | ctx].
__global__ __launch_bounds__(256) void attn_pass2(
    const float* __restrict__ scores, const float* __restrict__ chunkMax,
    const float* __restrict__ ctxPart, const float* __restrict__ rnn,
    float* __restrict__ attn, float* __restrict__ concat_in) {
    __shared__ float red[256];
    int b = blockIdx.x, tid = threadIdx.x;

    float v[4];
#pragma unroll
    for (int q = 0; q < 4; q++) v[q] = scores[(size_t)b * S_ + q * 256 + tid];
    float mx = fmaxf(fmaxf(v[0], v[1]), fmaxf(v[2], v[3]));
    red[tid] = mx; __syncthreads();
    for (int s = 128; s; s >>= 1) {
        if (tid < s) red[tid] = fmaxf(red[tid], red[tid + s]);
        __syncthreads();
    }
    float M = red[0]; __syncthreads();
    float e[4], sum = 0.f;
#pragma unroll
    for (int q = 0; q < 4; q++) { e[q] = __expf(v[q] - M); sum += e[q]; }
    red[tid] = sum; __syncthreads();
    for (int s = 128; s; s >>= 1) {
        if (tid < s) red[tid] += red[tid + s];
        __syncthreads();
    }
    float inv = 1.f / red[0];
#pragma unroll
    for (int q = 0; q < 4; q++) attn[(size_t)b * S_ + q * 256 + tid] = e[q] * inv;

    float4 acc = {0, 0, 0, 0};
#pragma unroll
    for (int c = 0; c < 16; c++) {
        float scl = __expf(chunkMax[b * 16 + c] - M);
        float4 part = *(const float4*)&ctxPart[((size_t)b * 16 + c) * H_ + tid * 4];
        acc.x += scl * part.x; acc.y += scl * part.y;
        acc.z += scl * part.z; acc.w += scl * part.w;
    }
    acc.x *= inv; acc.y *= inv; acc.z *= inv; acc.w *= inv;
    *(float4*)&concat_in[(size_t)b * 2048 + 1024 + tid * 4] = acc;
    *(float4*)&concat_in[(size_t)b * 2048 + tid * 4] =
        *(const float4*)&rnn[(size_t)b * H_ + tid * 4];
}

// ---------------------------------------------------------------------------
// Concat combine: sum 8 K-split partials + bias, tanh; emit exact bf16
// hi/lo split of the result for the MFMA output GEMM.
__global__ __launch_bounds__(256) void concat_combine_k(const float* __restrict__ P,
                                                        const float* __restrict__ bias,
                                                        ushort* __restrict__ Ahi,
                                                        ushort* __restrict__ Alo) {
    int idx = blockIdx.x * 256 + threadIdx.x;  // 65536
    int b = idx >> 10, h = idx & 1023;
    float s = 0.f;
#pragma unroll
    for (int kc = 0; kc < 8; kc++) s += P[(size_t)kc * 65536 + (size_t)b * H_ + h];
    float v = tanhf(s + bias[h]);
    ushort hi, lo;
    split_bf16(v, hi, lo);
    Ahi[idx] = hi;
    Alo[idx] = lo;
}

// ---------------------------------------------------------------------------
// Output GEMM v3: out[64][V] = (Ahi+Alo)[64][1024] x bf16(W[V][1024])^T + bias.
// Everything LDS-staged (A hi/lo AND W as bf16, converted during staging) so
// the inner loop is pure ds_read_b128 + MFMA — no global ops on the MFMA
// critical path. XOR-swizzled 16B slots (slot ^= row&7) -> conflict-free b128.
// Double-buffered, one barrier per 64-k tile; next-tile global loads issued
// before compute. Epilogue via LDS bounce: each wave stores one out row x
// 64 consecutive cols (256B contiguous) per instruction.
__global__ __launch_bounds__(256) void gemm_out_bf16(
    const ushort* __restrict__ Ahi, const ushort* __restrict__ Alo,
    const float* __restrict__ W, const float* __restrict__ bias,
    float* __restrict__ out) {
    __shared__ ushort AhL[2][64 * 64];  // 8 KB each buf
    __shared__ ushort AlL[2][64 * 64];
    __shared__ ushort WtL[2][64 * 64];  // total 48 KB

    int tid = threadIdx.x;
    int w = tid >> 6, l = tid & 63;
    int lr = l & 15;  // A row / W row (out col) within 16-tile
    int lk = l >> 4;  // k-subgroup 0..3

    int n0 = blockIdx.x * 64;

    // staging map: thread -> (row srow, k-quarter sq: 16 elems = slots 2sq,2sq+1)
    int srow = tid >> 2;  // 0..63
    int sq = tid & 3;     // 0..3
    int wrow_g = n0 + srow;
    const float* Wsrc = W + (size_t)(wrow_g < V_ ? wrow_g : 0) * H_;

    union SV { short8v v; ushort u[8]; };

    // staging registers
    short8v rAh0, rAh1, rAl0, rAl1;
    float4 rW[4];

    auto load_regs = [&](int kt) {
        int kb = kt * 64 + sq * 16;
        rAh0 = *(const short8v*)&Ahi[(size_t)srow * H_ + kb];
        rAh1 = *(const short8v*)&Ahi[(size_t)srow * H_ + kb + 8];
        rAl0 = *(const short8v*)&Alo[(size_t)srow * H_ + kb];
        rAl1 = *(const short8v*)&Alo[(size_t)srow * H_ + kb + 8];
#pragma unroll
        for (int i = 0; i < 4; i++) rW[i] = *(const float4*)&Wsrc[kb + i * 4];
    };

    auto write_lds = [&](int buf) {
        int s0 = (2 * sq) ^ (srow & 7);      // physical slot of logical 2sq
        int s1 = (2 * sq + 1) ^ (srow & 7);  // physical slot of logical 2sq+1
        int base = srow * 64;
        *(short8v*)&AhL[buf][base + s0 * 8] = rAh0;
        *(short8v*)&AhL[buf][base + s1 * 8] = rAh1;
        *(short8v*)&AlL[buf][base + s0 * 8] = rAl0;
        *(short8v*)&AlL[buf][base + s1 * 8] = rAl1;
        SV p0, p1;
        const float* f = (const float*)&rW[0];
#pragma unroll
        for (int j = 0; j < 8; j++) {
            p0.u[j] = rnd_bf16(f[j]);
            p1.u[j] = rnd_bf16(f[8 + j]);
        }
        *(short8v*)&WtL[buf][base + s0 * 8] = p0.v;
        *(short8v*)&WtL[buf][base + s1 * 8] = p1.v;
    };

    f32x4 acc[4];
#pragma unroll
    for (int mt = 0; mt < 4; mt++) acc[mt] = (f32x4){0.f, 0.f, 0.f, 0.f};

    load_regs(0);
    write_lds(0);
    __syncthreads();

    int wrow = w * 16 + lr;  // this lane's W row (block-local out col)
    for (int kt = 0; kt < NT_K; kt++) {
        if (kt + 1 < NT_K) load_regs(kt + 1);  // fly under compute

        int cur = kt & 1;
#pragma unroll
        for (int ks = 0; ks < 2; ks++) {
            int slot = ks * 4 + lk;  // logical 16B slot in row
            short8v wf = *(const short8v*)&WtL[cur][wrow * 64 + ((slot ^ (wrow & 7)) << 3)];
#pragma unroll
            for (int mt = 0; mt < 4; mt++) {
                int arow = mt * 16 + lr;
                int so = (slot ^ (arow & 7)) << 3;
                short8v ah = *(const short8v*)&AhL[cur][arow * 64 + so];
                short8v al = *(const short8v*)&AlL[cur][arow * 64 + so];
                acc[mt] = __builtin_amdgcn_mfma_f32_16x16x32_bf16(ah, wf, acc[mt], 0, 0, 0);
                acc[mt] = __builtin_amdgcn_mfma_f32_16x16x32_bf16(al, wf, acc[mt], 0, 0, 0);
            }
        }

        if (kt + 1 < NT_K) {
            write_lds((kt + 1) & 1);  // other buffer: its readers finished at kt-1
            __syncthreads();
        }
    }

    // Epilogue: bounce through LDS (reuse AhL = 16 KB) for coalesced stores.
    __syncthreads();
    float* et = (float*)&AhL[0][0];  // [64 rows][64 cols]
#pragma unroll
    for (int mt = 0; mt < 4; mt++) {
#pragma unroll
        for (int r = 0; r < 4; r++) {
            int row = mt * 16 + lk * 4 + r;
            et[row * 64 + wrow] = acc[mt][r];
        }
    }
    __syncthreads();

    int col = tid & 63;       // block-local out col
    int gc = n0 + col;
    int rg = tid >> 6;        // wave -> row group
    if (gc < V_) {
        float b = bias[gc];
#pragma unroll
        for (int rr = 0; rr < 16; rr++) {
            int orow = rg * 16 + rr;
            out[(size_t)orow * V_ + gc] = et[orow * 64 + col] + b;
        }
    }
}

// ---------------------------------------------------------------------------
extern "C" void kernel_launch(void* const* d_in, const int* in_sizes, int n_in,
                              void* d_out, int out_size, void* d_ws, size_t ws_size,
                              hipStream_t stream) {
    const int* seq = (const int*)d_in[0];
    const float* last_hidden = (const float*)d_in[1];
    const float* enc = (const float*)d_in[2];
    const float* emb = (const float*)d_in[3];
    const float* w_ih = (const float*)d_in[4];
    const float* w_hh = (const float*)d_in[5];
    const float* b_ih = (const float*)d_in[6];
    const float* b_hh = (const float*)d_in[7];
    const float* concat_w = (const float*)d_in[8];
    const float* concat_b = (const float*)d_in[9];
    const float* out_w = (const float*)d_in[10];
    const float* out_b = (const float*)d_in[11];

    float* out = (float*)d_out;                           // (B,V)
    float* out_hidden = out + (size_t)B_ * V_;            // (L,B,H)
    float* out_attn = out_hidden + (size_t)L_ * B_ * H_;  // (B,1,S)

    float* ws = (float*)d_ws;
    float* x0 = ws;                        // 65536
    float* gatesP = x0 + 65536;            // 4*64*6144 = 1572864
    float* scores = gatesP + 1572864;      // 65536
    float* chunkMax = scores + 65536;      // 1024
    float* ctxPart = chunkMax + 1024;      // 1048576
    float* concat_in = ctxPart + 1048576;  // 131072
    float* concatP = concat_in + 131072;   // 524288
    ushort* Ahi = (ushort*)(concatP + 524288);  // 65536 ushort
    ushort* Alo = Ahi + 65536;                  // 65536 ushort

    // 1. Embedding
    embed_k<<<256, 256, 0, stream>>>(seq, emb, x0);

    // 2. GRU layers
    for (int l = 0; l < L_; l++) {
        const float* xl = (l == 0) ? x0 : out_hidden + (size_t)(l - 1) * B_ * H_;
        const float* hl = last_hidden + (size_t)l * B_ * H_;
        gemm_m64<<<dim3(N_GATES / 64, 4), 256, 0, stream>>>(
            xl, hl, H_,
            w_ih + (size_t)l * G3H * H_, w_hh + (size_t)l * G3H * H_, H_, G3H,
            gatesP, N_GATES, H_);
        gru_combine_k<<<256, 256, 0, stream>>>(gatesP, b_ih + (size_t)l * G3H,
                                               b_hh + (size_t)l * G3H, hl,
                                               out_hidden + (size_t)l * B_ * H_);
    }
    const float* rnn = out_hidden + (size_t)2 * B_ * H_;

    // 3. Fused attention (single enc pass) + combine/assemble
    attn_pass1<<<1024, 256, 0, stream>>>(rnn, enc, scores, ctxPart, chunkMax);
    attn_pass2<<<64, 256, 0, stream>>>(scores, chunkMax, ctxPart, rnn,
                                       out_attn, concat_in);

    // 4. Concat GEMM (K=2048, 8-way K-split) + tanh combine (+ bf16 split)
    gemm_m64<<<dim3(16, 8), 256, 0, stream>>>(
        concat_in, concat_in, 2048, concat_w, concat_w, 2048, 1 << 30,
        concatP, H_, 2048);
    concat_combine_k<<<256, 256, 0, stream>>>(concatP, concat_b, Ahi, Alo);

    // 5. Output GEMM v3: all-LDS inner loop, coalesced epilogue
    gemm_out_bf16<<<(V_ + 63) / 64, 256, 0, stream>>>(Ahi, Alo, out_w, out_b, out);
}

// Round 9
// 183.472 us; speedup vs baseline: 1.9124x; 1.1923x over previous
//
#include <hip/hip_runtime.h>
#include <hip/hip_bf16.h>
#include <float.h>

#define B_ 64
#define H_ 1024
#define S_ 1024
#define V_ 50257
#define L_ 3
#define G3H 3072      // 3*H
#define N_GATES 6144  // 2*3H fused gi|gh
#define NT_K 16       // 1024 / 64 k-tiles in output GEMM
#define KSPL_GRU 8    // K-split for GRU gates GEMM
#define KSPL_CAT 16   // K-split for concat GEMM

typedef __attribute__((ext_vector_type(8))) short short8v;  // 8 bf16 (4 VGPRs)
typedef __attribute__((ext_vector_type(4))) float f32x4;    // MFMA accumulator

// round-to-nearest f32 -> bf16 bits
__device__ __forceinline__ ushort rnd_bf16(float x) {
    uint u = __float_as_uint(x);
    return (ushort)((u + 0x7fffu + ((u >> 16) & 1u)) >> 16);
}

// exact split x = hi + lo (hi = truncated bf16, lo = rounded residual)
__device__ __forceinline__ void split_bf16(float x, ushort& hi, ushort& lo) {
    uint u = __float_as_uint(x);
    uint h = u & 0xffff0000u;
    hi = (ushort)(h >> 16);
    float r = x - __uint_as_float(h);
    uint ur = __float_as_uint(r);
    lo = (ushort)((ur + 0x7fffu + ((ur >> 16) & 1u)) >> 16);
}

// ---------------------------------------------------------------------------
// Generic M=64 bf16-MFMA GEMM, all-LDS inner loop (v3 template from the
// output GEMM): Cpart[ky][64][N] = A[64][K] x W[N][K]^T partials.
// A fp32 -> exact hi/lo bf16 split during staging; W fp32 -> rounded bf16.
// Dual-A/W via Nhalf (block col >= Nhalf uses A1/W1). Optional seq row
// gather on A0 (embedding fusion). XOR-swizzled 16B slots, double-buffered,
// one barrier per 64-k tile. N must be a multiple of 64; K/gridDim.y of 64.
__global__ __launch_bounds__(256) void gemm_bf16_lds(
    const float* __restrict__ A0, const int* __restrict__ seq,
    const float* __restrict__ A1, int lda,
    const float* __restrict__ W0, const float* __restrict__ W1, int ldw,
    int Nhalf, float* __restrict__ Cpart, int N, int K) {
    __shared__ ushort AhL[2][64 * 64];
    __shared__ ushort AlL[2][64 * 64];
    __shared__ ushort WtL[2][64 * 64];  // 48 KB total

    int tid = threadIdx.x;
    int w = tid >> 6, l = tid & 63;
    int lr = l & 15;  // A row / W row within 16-tile
    int lk = l >> 4;  // k-subgroup 0..3

    int n0 = blockIdx.x * 64;
    const float* A = A0;
    const float* W = W0;
    const int* sq = seq;
    int ncol0 = n0;
    if (n0 >= Nhalf) { A = A1; W = W1; ncol0 = n0 - Nhalf; sq = nullptr; }

    // staging map: thread -> (row srow, k-quarter sqk: 16 floats)
    int srow = tid >> 2;  // 0..63
    int sqk = tid & 3;    // 0..3
    const float* Asrc = A + (size_t)(sq ? sq[srow] : srow) * lda;
    const float* Wsrc = W + (size_t)(ncol0 + srow) * ldw;

    int kChunk = K / gridDim.y;
    int kBeg = blockIdx.y * kChunk;
    int nt = kChunk >> 6;  // 64-k tiles

    union SV { short8v v; ushort u[8]; };

    float4 rA[4], rW[4];
    auto load_regs = [&](int kt) {
        int kb = kBeg + kt * 64 + sqk * 16;
#pragma unroll
        for (int i = 0; i < 4; i++) {
            rA[i] = *(const float4*)&Asrc[kb + i * 4];
            rW[i] = *(const float4*)&Wsrc[kb + i * 4];
        }
    };
    auto write_lds = [&](int buf) {
        int s0 = (2 * sqk) ^ (srow & 7);
        int s1 = (2 * sqk + 1) ^ (srow & 7);
        int base = srow * 64;
        SV h0, h1, l0, l1, q0, q1;
        const float* fa = (const float*)&rA[0];
        const float* fw = (const float*)&rW[0];
#pragma unroll
        for (int j = 0; j < 8; j++) {
            split_bf16(fa[j], h0.u[j], l0.u[j]);
            split_bf16(fa[8 + j], h1.u[j], l1.u[j]);
            q0.u[j] = rnd_bf16(fw[j]);
            q1.u[j] = rnd_bf16(fw[8 + j]);
        }
        *(short8v*)&AhL[buf][base + s0 * 8] = h0.v;
        *(short8v*)&AhL[buf][base + s1 * 8] = h1.v;
        *(short8v*)&AlL[buf][base + s0 * 8] = l0.v;
        *(short8v*)&AlL[buf][base + s1 * 8] = l1.v;
        *(short8v*)&WtL[buf][base + s0 * 8] = q0.v;
        *(short8v*)&WtL[buf][base + s1 * 8] = q1.v;
    };

    f32x4 acc[4];
#pragma unroll
    for (int mt = 0; mt < 4; mt++) acc[mt] = (f32x4){0.f, 0.f, 0.f, 0.f};

    load_regs(0);
    write_lds(0);
    __syncthreads();

    int wrow = w * 16 + lr;  // block-local output col
    for (int kt = 0; kt < nt; kt++) {
        if (kt + 1 < nt) load_regs(kt + 1);  // fly under compute

        int cur = kt & 1;
#pragma unroll
        for (int ks = 0; ks < 2; ks++) {
            int slot = ks * 4 + lk;
            short8v wf = *(const short8v*)&WtL[cur][wrow * 64 + ((slot ^ (wrow & 7)) << 3)];
#pragma unroll
            for (int mt = 0; mt < 4; mt++) {
                int arow = mt * 16 + lr;
                int so = (slot ^ (arow & 7)) << 3;
                short8v ah = *(const short8v*)&AhL[cur][arow * 64 + so];
                short8v al = *(const short8v*)&AlL[cur][arow * 64 + so];
                acc[mt] = __builtin_amdgcn_mfma_f32_16x16x32_bf16(ah, wf, acc[mt], 0, 0, 0);
                acc[mt] = __builtin_amdgcn_mfma_f32_16x16x32_bf16(al, wf, acc[mt], 0, 0, 0);
            }
        }

        if (kt + 1 < nt) {
            write_lds((kt + 1) & 1);
            __syncthreads();
        }
    }

    // raw partial store (small buffers, L2-resident)
    float* Pp = Cpart + (size_t)blockIdx.y * 64 * N;
    int col = n0 + wrow;
#pragma unroll
    for (int mt = 0; mt < 4; mt++) {
#pragma unroll
        for (int r = 0; r < 4; r++) {
            int row = mt * 16 + lk * 4 + r;
            Pp[(size_t)row * N + col] = acc[mt][r];
        }
    }
}

// ---------------------------------------------------------------------------
// GRU gate combine: 8 K-split partials of fused [gi | gh] + biases -> h_out
__global__ __launch_bounds__(256) void gru_combine_k(
    const float* __restrict__ P, const float* __restrict__ b_ih,
    const float* __restrict__ b_hh, const float* __restrict__ hprev,
    float* __restrict__ hout) {
    int idx = blockIdx.x * 256 + threadIdx.x;  // 65536
    int b = idx >> 10, j = idx & 1023;
    const size_t stride = (size_t)64 * N_GATES;
    const float* rowp = P + (size_t)b * N_GATES;

    float ir = 0.f, iz = 0.f, in_ = 0.f, hr = 0.f, hz = 0.f, hn = 0.f;
#pragma unroll
    for (int kc = 0; kc < KSPL_GRU; kc++) {
        const float* p = rowp + kc * stride;
        ir += p[j];        iz += p[j + 1024];        in_ += p[j + 2048];
        hr += p[3072 + j]; hz += p[3072 + j + 1024]; hn += p[3072 + j + 2048];
    }
    ir += b_ih[j]; iz += b_ih[j + 1024]; in_ += b_ih[j + 2048];
    hr += b_hh[j]; hz += b_hh[j + 1024]; hn += b_hh[j + 2048];

    float r = 1.f / (1.f + __expf(-(ir + hr)));
    float z = 1.f / (1.f + __expf(-(iz + hz)));
    float n = tanhf(in_ + r * hn);
    float hp = hprev[idx];
    hout[idx] = (1.f - z) * n + z * hp;
}

// ---------------------------------------------------------------------------
// Fused attention pass 1: one enc read -> raw scores + online-softmax context
// partials. grid = 64 b * 16 sc; 4 waves/block, each wave owns 16 s rows.
__global__ __launch_bounds__(256) void attn_pass1(
    const float* __restrict__ rnn, const float* __restrict__ enc,
    float* __restrict__ scores, float* __restrict__ ctxPart,
    float* __restrict__ chunkMax) {
    __shared__ float lm[4];
    __shared__ float lc[4][1024];

    int bid = blockIdx.x;
    int b = bid >> 4, scv = bid & 15;
    int tid = threadIdx.x;
    int w = tid >> 6, lane = tid & 63;

    const float4* rr = (const float4*)(rnn + (size_t)b * H_);
    float4 r0 = rr[0 * 64 + lane], r1 = rr[1 * 64 + lane];
    float4 r2 = rr[2 * 64 + lane], r3 = rr[3 * 64 + lane];

    float m = -FLT_MAX;
    float4 c0 = {0, 0, 0, 0}, c1 = {0, 0, 0, 0}, c2 = {0, 0, 0, 0}, c3 = {0, 0, 0, 0};

    int s0 = scv * 64 + w * 16;
    for (int si = 0; si < 16; si++) {
        int s = s0 + si;
        const float4* er = (const float4*)(enc + ((size_t)s * B_ + b) * H_);
        float4 e0 = er[0 * 64 + lane], e1 = er[1 * 64 + lane];
        float4 e2 = er[2 * 64 + lane], e3 = er[3 * 64 + lane];

        float d = e0.x * r0.x + e0.y * r0.y + e0.z * r0.z + e0.w * r0.w;
        d += e1.x * r1.x + e1.y * r1.y + e1.z * r1.z + e1.w * r1.w;
        d += e2.x * r2.x + e2.y * r2.y + e2.z * r2.z + e2.w * r2.w;
        d += e3.x * r3.x + e3.y * r3.y + e3.z * r3.z + e3.w * r3.w;
#pragma unroll
        for (int off = 32; off; off >>= 1) d += __shfl_xor(d, off, 64);
        if (lane == 0) scores[(size_t)b * S_ + s] = d;

        if (d > m) {  // wave-uniform (d identical on all lanes)
            float scale = __expf(m - d);
            c0.x *= scale; c0.y *= scale; c0.z *= scale; c0.w *= scale;
            c1.x *= scale; c1.y *= scale; c1.z *= scale; c1.w *= scale;
            c2.x *= scale; c2.y *= scale; c2.z *= scale; c2.w *= scale;
            c3.x *= scale; c3.y *= scale; c3.z *= scale; c3.w *= scale;
            m = d;
        }
        float p = __expf(d - m);
        c0.x += p * e0.x; c0.y += p * e0.y; c0.z += p * e0.z; c0.w += p * e0.w;
        c1.x += p * e1.x; c1.y += p * e1.y; c1.z += p * e1.z; c1.w += p * e1.w;
        c2.x += p * e2.x; c2.y += p * e2.y; c2.z += p * e2.z; c2.w += p * e2.w;
        c3.x += p * e3.x; c3.y += p * e3.y; c3.z += p * e3.z; c3.w += p * e3.w;
    }

    if (lane == 0) lm[w] = m;
    __syncthreads();
    float M = fmaxf(fmaxf(lm[0], lm[1]), fmaxf(lm[2], lm[3]));
    float sw = __expf(m - M);
    float4* lw = (float4*)&lc[w][0];
    float4 t;
    t.x = c0.x * sw; t.y = c0.y * sw; t.z = c0.z * sw; t.w = c0.w * sw; lw[0 * 64 + lane] = t;
    t.x = c1.x * sw; t.y = c1.y * sw; t.z = c1.z * sw; t.w = c1.w * sw; lw[1 * 64 + lane] = t;
    t.x = c2.x * sw; t.y = c2.y * sw; t.z = c2.z * sw; t.w = c2.w * sw; lw[2 * 64 + lane] = t;
    t.x = c3.x * sw; t.y = c3.y * sw; t.z = c3.z * sw; t.w = c3.w * sw; lw[3 * 64 + lane] = t;
    __syncthreads();

    float4 s4 = *(const float4*)&lc[0][tid * 4];
    float4 a1 = *(const float4*)&lc[1][tid * 4];
    float4 a2 = *(const float4*)&lc[2][tid * 4];
    float4 a3 = *(const float4*)&lc[3][tid * 4];
    s4.x += a1.x + a2.x + a3.x; s4.y += a1.y + a2.y + a3.y;
    s4.z += a1.z + a2.z + a3.z; s4.w += a1.w + a2.w + a3.w;
    *(float4*)&ctxPart[(size_t)bid * H_ + tid * 4] = s4;
    if (tid == 0) chunkMax[bid] = M;
}

// ---------------------------------------------------------------------------
// Attention pass 2 (per b): global softmax -> attn output, rescale+sum chunk
// contexts, assemble concat_in = [rnn | ctx].
__global__ __launch_bounds__(256) void attn_pass2(
    const float* __restrict__ scores, const float* __restrict__ chunkMax,
    const float* __restrict__ ctxPart, const float* __restrict__ rnn,
    float* __restrict__ attn, float* __restrict__ concat_in) {
    __shared__ float red[256];
    int b = blockIdx.x, tid = threadIdx.x;

    float v[4];
#pragma unroll
    for (int q = 0; q < 4; q++) v[q] = scores[(size_t)b * S_ + q * 256 + tid];
    float mx = fmaxf(fmaxf(v[0], v[1]), fmaxf(v[2], v[3]));
    red[tid] = mx; __syncthreads();
    for (int s = 128; s; s >>= 1) {
        if (tid < s) red[tid] = fmaxf(red[tid], red[tid + s]);
        __syncthreads();
    }
    float M = red[0]; __syncthreads();
    float e[4], sum = 0.f;
#pragma unroll
    for (int q = 0; q < 4; q++) { e[q] = __expf(v[q] - M); sum += e[q]; }
    red[tid] = sum; __syncthreads();
    for (int s = 128; s; s >>= 1) {
        if (tid < s) red[tid] += red[tid + s];
        __syncthreads();
    }
    float inv = 1.f / red[0];
#pragma unroll
    for (int q = 0; q < 4; q++) attn[(size_t)b * S_ + q * 256 + tid] = e[q] * inv;

    float4 acc = {0, 0, 0, 0};
#pragma unroll
    for (int c = 0; c < 16; c++) {
        float scl = __expf(chunkMax[b * 16 + c] - M);
        float4 part = *(const float4*)&ctxPart[((size_t)b * 16 + c) * H_ + tid * 4];
        acc.x += scl * part.x; acc.y += scl * part.y;
        acc.z += scl * part.z; acc.w += scl * part.w;
    }
    acc.x *= inv; acc.y *= inv; acc.z *= inv; acc.w *= inv;
    *(float4*)&concat_in[(size_t)b * 2048 + 1024 + tid * 4] = acc;
    *(float4*)&concat_in[(size_t)b * 2048 + tid * 4] =
        *(const float4*)&rnn[(size_t)b * H_ + tid * 4];
}

// ---------------------------------------------------------------------------
// Concat combine: sum 16 K-split partials + bias, tanh; emit exact bf16
// hi/lo split of the result for the MFMA output GEMM.
__global__ __launch_bounds__(256) void concat_combine_k(const float* __restrict__ P,
                                                        const float* __restrict__ bias,
                                                        ushort* __restrict__ Ahi,
                                                        ushort* __restrict__ Alo) {
    int idx = blockIdx.x * 256 + threadIdx.x;  // 65536
    int b = idx >> 10, h = idx & 1023;
    float s = 0.f;
#pragma unroll
    for (int kc = 0; kc < KSPL_CAT; kc++) s += P[(size_t)kc * 65536 + (size_t)b * H_ + h];
    float v = tanhf(s + bias[h]);
    ushort hi, lo;
    split_bf16(v, hi, lo);
    Ahi[idx] = hi;
    Alo[idx] = lo;
}

// ---------------------------------------------------------------------------
// Output GEMM v3 (unchanged from R8): all-LDS inner loop, coalesced epilogue.
__global__ __launch_bounds__(256) void gemm_out_bf16(
    const ushort* __restrict__ Ahi, const ushort* __restrict__ Alo,
    const float* __restrict__ W, const float* __restrict__ bias,
    float* __restrict__ out) {
    __shared__ ushort AhL[2][64 * 64];
    __shared__ ushort AlL[2][64 * 64];
    __shared__ ushort WtL[2][64 * 64];

    int tid = threadIdx.x;
    int w = tid >> 6, l = tid & 63;
    int lr = l & 15;
    int lk = l >> 4;

    int n0 = blockIdx.x * 64;

    int srow = tid >> 2;
    int sqk = tid & 3;
    int wrow_g = n0 + srow;
    const float* Wsrc = W + (size_t)(wrow_g < V_ ? wrow_g : 0) * H_;

    union SV { short8v v; ushort u[8]; };

    short8v rAh0, rAh1, rAl0, rAl1;
    float4 rW[4];

    auto load_regs = [&](int kt) {
        int kb = kt * 64 + sqk * 16;
        rAh0 = *(const short8v*)&Ahi[(size_t)srow * H_ + kb];
        rAh1 = *(const short8v*)&Ahi[(size_t)srow * H_ + kb + 8];
        rAl0 = *(const short8v*)&Alo[(size_t)srow * H_ + kb];
        rAl1 = *(const short8v*)&Alo[(size_t)srow * H_ + kb + 8];
#pragma unroll
        for (int i = 0; i < 4; i++) rW[i] = *(const float4*)&Wsrc[kb + i * 4];
    };

    auto write_lds = [&](int buf) {
        int s0 = (2 * sqk) ^ (srow & 7);
        int s1 = (2 * sqk + 1) ^ (srow & 7);
        int base = srow * 64;
        *(short8v*)&AhL[buf][base + s0 * 8] = rAh0;
        *(short8v*)&AhL[buf][base + s1 * 8] = rAh1;
        *(short8v*)&AlL[buf][base + s0 * 8] = rAl0;
        *(short8v*)&AlL[buf][base + s1 * 8] = rAl1;
        SV p0, p1;
        const float* f = (const float*)&rW[0];
#pragma unroll
        for (int j = 0; j < 8; j++) {
            p0.u[j] = rnd_bf16(f[j]);
            p1.u[j] = rnd_bf16(f[8 + j]);
        }
        *(short8v*)&WtL[buf][base + s0 * 8] = p0.v;
        *(short8v*)&WtL[buf][base + s1 * 8] = p1.v;
    };

    f32x4 acc[4];
#pragma unroll
    for (int mt = 0; mt < 4; mt++) acc[mt] = (f32x4){0.f, 0.f, 0.f, 0.f};

    load_regs(0);
    write_lds(0);
    __syncthreads();

    int wrow = w * 16 + lr;
    for (int kt = 0; kt < NT_K; kt++) {
        if (kt + 1 < NT_K) load_regs(kt + 1);

        int cur = kt & 1;
#pragma unroll
        for (int ks = 0; ks < 2; ks++) {
            int slot = ks * 4 + lk;
            short8v wf = *(const short8v*)&WtL[cur][wrow * 64 + ((slot ^ (wrow & 7)) << 3)];
#pragma unroll
            for (int mt = 0; mt < 4; mt++) {
                int arow = mt * 16 + lr;
                int so = (slot ^ (arow & 7)) << 3;
                short8v ah = *(const short8v*)&AhL[cur][arow * 64 + so];
                short8v al = *(const short8v*)&AlL[cur][arow * 64 + so];
                acc[mt] = __builtin_amdgcn_mfma_f32_16x16x32_bf16(ah, wf, acc[mt], 0, 0, 0);
                acc[mt] = __builtin_amdgcn_mfma_f32_16x16x32_bf16(al, wf, acc[mt], 0, 0, 0);
            }
        }

        if (kt + 1 < NT_K) {
            write_lds((kt + 1) & 1);
            __syncthreads();
        }
    }

    __syncthreads();
    float* et = (float*)&AhL[0][0];
#pragma unroll
    for (int mt = 0; mt < 4; mt++) {
#pragma unroll
        for (int r = 0; r < 4; r++) {
            int row = mt * 16 + lk * 4 + r;
            et[row * 64 + wrow] = acc[mt][r];
        }
    }
    __syncthreads();

    int col = tid & 63;
    int gc = n0 + col;
    int rg = tid >> 6;
    if (gc < V_) {
        float b = bias[gc];
#pragma unroll
        for (int rr = 0; rr < 16; rr++) {
            int orow = rg * 16 + rr;
            out[(size_t)orow * V_ + gc] = et[orow * 64 + col] + b;
        }
    }
}

// ---------------------------------------------------------------------------
extern "C" void kernel_launch(void* const* d_in, const int* in_sizes, int n_in,
                              void* d_out, int out_size, void* d_ws, size_t ws_size,
                              hipStream_t stream) {
    const int* seq = (const int*)d_in[0];
    const float* last_hidden = (const float*)d_in[1];
    const float* enc = (const float*)d_in[2];
    const float* emb = (const float*)d_in[3];
    const float* w_ih = (const float*)d_in[4];
    const float* w_hh = (const float*)d_in[5];
    const float* b_ih = (const float*)d_in[6];
    const float* b_hh = (const float*)d_in[7];
    const float* concat_w = (const float*)d_in[8];
    const float* concat_b = (const float*)d_in[9];
    const float* out_w = (const float*)d_in[10];
    const float* out_b = (const float*)d_in[11];

    float* out = (float*)d_out;                           // (B,V)
    float* out_hidden = out + (size_t)B_ * V_;            // (L,B,H)
    float* out_attn = out_hidden + (size_t)L_ * B_ * H_;  // (B,1,S)

    float* ws = (float*)d_ws;
    float* gatesP = ws;                    // 8*64*6144 = 3145728
    float* scores = gatesP + 3145728;      // 65536
    float* chunkMax = scores + 65536;      // 1024
    float* ctxPart = chunkMax + 1024;      // 1048576
    float* concat_in = ctxPart + 1048576;  // 131072
    float* concatP = concat_in + 131072;   // 16*64*1024 = 1048576
    ushort* Ahi = (ushort*)(concatP + 1048576);  // 65536 ushort
    ushort* Alo = Ahi + 65536;                   // 65536 ushort

    // 1+2. GRU layers (layer 0 fuses the embedding gather via seq)
    for (int l = 0; l < L_; l++) {
        const float* xl = (l == 0) ? emb : out_hidden + (size_t)(l - 1) * B_ * H_;
        const int* sq = (l == 0) ? seq : nullptr;
        const float* hl = last_hidden + (size_t)l * B_ * H_;
        gemm_bf16_lds<<<dim3(N_GATES / 64, KSPL_GRU), 256, 0, stream>>>(
            xl, sq, hl, H_,
            w_ih + (size_t)l * G3H * H_, w_hh + (size_t)l * G3H * H_, H_, G3H,
            gatesP, N_GATES, H_);
        gru_combine_k<<<256, 256, 0, stream>>>(gatesP, b_ih + (size_t)l * G3H,
                                               b_hh + (size_t)l * G3H, hl,
                                               out_hidden + (size_t)l * B_ * H_);
    }
    const float* rnn = out_hidden + (size_t)2 * B_ * H_;

    // 3. Fused attention (single enc pass) + combine/assemble
    attn_pass1<<<1024, 256, 0, stream>>>(rnn, enc, scores, ctxPart, chunkMax);
    attn_pass2<<<64, 256, 0, stream>>>(scores, chunkMax, ctxPart, rnn,
                                       out_attn, concat_in);

    // 4. Concat GEMM (K=2048, 16-way K-split) + tanh combine (+ bf16 split)
    gemm_bf16_lds<<<dim3(H_ / 64, KSPL_CAT), 256, 0, stream>>>(
        concat_in, nullptr, concat_in, 2048, concat_w, concat_w, 2048, 1 << 30,
        concatP, H_, 2048);
    concat_combine_k<<<256, 256, 0, stream>>>(concatP, concat_b, Ahi, Alo);

    // 5. Output GEMM v3: all-LDS inner loop, coalesced epilogue
    gemm_out_bf16<<<(V_ + 63) / 64, 256, 0, stream>>>(Ahi, Alo, out_w, out_b, out);
}